// Round 4
// baseline (3136.477 us; speedup 1.0000x reference)
//
#include <hip/hip_runtime.h>

#define R_CHUNKS 8

// ws layout (floats):
//   part[BT*8]  at ws[0 .. BT*8)        per-chunk sum(exp(x)) (0 if row masked)
//   xt[BT]      at ws[BT*8 .. BT*9)     target logit per row  (0 if masked)
//   mse[BL]     at ws[BT*9 .. BT*9+BL)  per-patch mse         (0 if masked)
//   counter     at ws[BT*9+BL]          (unsigned; zeroed via hipMemsetAsync each call)
// Every data slot is written on every call -> graph-replay safe.

__device__ __forceinline__ float sum4exp(float4 v) {
    return __expf(v.x) + __expf(v.y) + __expf(v.z) + __expf(v.w);
}

__global__ __launch_bounds__(256) void fused_kernel(
    const float* __restrict__ pred,    // [BT, V]
    const int*   __restrict__ tgt,     // [BT]
    const float* __restrict__ rmask,   // [BT]
    const float* __restrict__ itrue,   // [BL, D]
    const float* __restrict__ ipred,   // [BL, D]
    const float* __restrict__ imask,   // [BL]
    float* __restrict__ part,          // [BT*8]
    float* __restrict__ xt,            // [BT]
    float* __restrict__ mse_out,       // [BL]
    unsigned int* __restrict__ counter,
    const float* __restrict__ iw, const float* __restrict__ rw,
    float* __restrict__ out,
    int V, int BT, int D, int BL, int mse_blocks, int total_blocks)
{
    const int bid = blockIdx.x;
    const int tid = threadIdx.x;
    __shared__ float red[4];
    __shared__ unsigned int sprev;

    if (bid < mse_blocks) {
        // ---------------- MSE: 4 patches per block, one wave each ----------------
        const int lane  = tid & 63;
        const int patch = bid * 4 + (tid >> 6);
        if (patch < BL) {
            const float mk = imask[patch];
            if (mk == 0.0f) {
                if (lane == 0) mse_out[patch] = 0.0f;
            } else {
                const float4* t4 = (const float4*)(itrue + (size_t)patch * D);
                const float4* p4 = (const float4*)(ipred + (size_t)patch * D);
                const int nd4 = D >> 2;                    // 192
                float acc = 0.0f;
                for (int i = lane; i < nd4; i += 64) {     // 3 iters
                    float4 a = t4[i], b = p4[i];
                    float dx = b.x - a.x, dy = b.y - a.y, dz = b.z - a.z, dw = b.w - a.w;
                    acc += dx * dx + dy * dy + dz * dz + dw * dw;
                }
                #pragma unroll
                for (int off = 32; off > 0; off >>= 1) acc += __shfl_down(acc, off);
                if (lane == 0) mse_out[patch] = acc / (float)D;
            }
        }
    } else {
        // ---------------- CE chunk: 1/8 of one vocab row (16 KB) ----------------
        const int cid   = bid - mse_blocks;
        const int row   = cid >> 3;
        const int chunk = cid & 7;
        const float mk  = rmask[row];
        if (mk == 0.0f) {
            if (tid == 0) {
                part[cid] = 0.0f;
                if (chunk == 0) xt[row] = 0.0f;
            }
        } else {
            const int VC = V / R_CHUNKS;                   // 4000
            const float4* p4 = (const float4*)(pred + (size_t)row * V + (size_t)chunk * VC);
            const int nv4 = VC >> 2;                       // 1000
            // each thread: 4 contiguous float4 (64B), all 4 loads independent & in flight
            float s0 = 0.f, s1 = 0.f, s2 = 0.f, s3 = 0.f;
            for (int i = tid * 4; i < nv4; i += 1024) {
                const int i1 = min(i + 1, nv4 - 1);
                const int i2 = min(i + 2, nv4 - 1);
                const int i3 = min(i + 3, nv4 - 1);
                float4 a = p4[i], b = p4[i1], c = p4[i2], d = p4[i3];
                s0 += sum4exp(a);
                if (i + 1 < nv4) s1 += sum4exp(b);
                if (i + 2 < nv4) s2 += sum4exp(c);
                if (i + 3 < nv4) s3 += sum4exp(d);
            }
            float s = (s0 + s1) + (s2 + s3);
            #pragma unroll
            for (int off = 32; off > 0; off >>= 1) s += __shfl_down(s, off);
            const int wid = tid >> 6;
            if ((tid & 63) == 0) red[wid] = s;
            __syncthreads();
            if (tid == 0) {
                part[cid] = (red[0] + red[1]) + (red[2] + red[3]);
                if (chunk == 0) xt[row] = pred[(size_t)row * V + tgt[row]];
            }
        }
    }

    // ---------------- last-block finalize (threadFenceReduction idiom) ----------
    __threadfence();                 // release: flush this block's global writes
    __syncthreads();
    if (tid == 0) sprev = atomicAdd(counter, 1u);   // device-scope by default
    __syncthreads();
    if (sprev != (unsigned int)(total_blocks - 1)) return;

    __threadfence();                 // acquire: see all other blocks' writes
    float a = 0.f, bm = 0.f, c = 0.f, dm = 0.f;
    const float4* part4 = (const float4*)part;      // 2 float4 per row
    for (int r = tid; r < BT; r += 256) {           // 16 iters
        float mk = rmask[r];
        bm += mk;
        if (mk != 0.0f) {
            float4 x = part4[r * 2], y = part4[r * 2 + 1];
            float S = ((x.x + x.y) + (x.z + x.w)) + ((y.x + y.y) + (y.z + y.w));
            a += (__logf(S) - xt[r]) * mk;
        }
    }
    for (int i = tid; i < BL; i += 256) { c += mse_out[i]; dm += imask[i]; }
    #pragma unroll
    for (int off = 32; off > 0; off >>= 1) {
        a  += __shfl_down(a, off);  bm += __shfl_down(bm, off);
        c  += __shfl_down(c, off);  dm += __shfl_down(dm, off);
    }
    __shared__ float fa[4], fb[4], fc[4], fd[4];
    const int wid = tid >> 6;
    if ((tid & 63) == 0) { fa[wid] = a; fb[wid] = bm; fc[wid] = c; fd[wid] = dm; }
    __syncthreads();
    if (tid == 0) {
        float A  = (fa[0] + fa[1]) + (fa[2] + fa[3]);
        float Bm = (fb[0] + fb[1]) + (fb[2] + fb[3]);
        float Cm = (fc[0] + fc[1]) + (fc[2] + fc[3]);
        float Dm = (fd[0] + fd[1]) + (fd[2] + fd[3]);
        out[0] = A / Bm * rw[0] + Cm / Dm * iw[0];
    }
}

extern "C" void kernel_launch(void* const* d_in, const int* in_sizes, int n_in,
                              void* d_out, int out_size, void* d_ws, size_t ws_size,
                              hipStream_t stream) {
    const float* images_true    = (const float*)d_in[0];
    const int*   reports_true   = (const int*)  d_in[1];
    const float* images_pred    = (const float*)d_in[2];
    const float* reports_pred   = (const float*)d_in[3];
    const float* images_mask    = (const float*)d_in[4];
    const float* reports_mask   = (const float*)d_in[5];
    const float* images_weight  = (const float*)d_in[6];
    const float* reports_weight = (const float*)d_in[7];

    float* out = (float*)d_out;
    float* ws  = (float*)d_ws;

    const int BT = in_sizes[1];                 // 4096
    const int V  = in_sizes[3] / BT;            // 32000
    const int BL = in_sizes[4];                 // 6272
    const int D  = in_sizes[0] / BL;            // 768

    float* part    = ws;                                    // [BT*8]
    float* xt      = ws + (size_t)BT * R_CHUNKS;            // [BT]
    float* mse_arr = ws + (size_t)BT * (R_CHUNKS + 1);      // [BL]
    unsigned int* counter = (unsigned int*)(ws + (size_t)BT * (R_CHUNKS + 1) + BL);

    hipMemsetAsync(counter, 0, sizeof(unsigned int), stream);

    const int mse_blocks   = (BL + 3) / 4;                  // 1568
    const int total_blocks = mse_blocks + BT * R_CHUNKS;    // 34336
    fused_kernel<<<total_blocks, 256, 0, stream>>>(
        reports_pred, reports_true, reports_mask,
        images_true, images_pred, images_mask,
        part, xt, mse_arr, counter,
        images_weight, reports_weight, out,
        V, BT, D, BL, mse_blocks, total_blocks);
}

// Round 5
// 54.642 us; speedup vs baseline: 57.4003x; 57.4003x over previous
//
#include <hip/hip_runtime.h>

#define R_CHUNKS 8

// ws layout (floats):
//   part[BT*8]  at ws[0 .. BT*8)        per-chunk sum(exp(x)) (0 if row masked)
//   xt[BT]      at ws[BT*8 .. BT*9)     target logit per row  (0 if masked)
//   mse[BL]     at ws[BT*9 .. BT*9+BL)  per-patch mse         (0 if masked)
// Every slot written on every call -> no zeroing, graph-replay safe.

__device__ __forceinline__ float sum4exp(float4 v) {
    return __expf(v.x) + __expf(v.y) + __expf(v.z) + __expf(v.w);
}

__global__ __launch_bounds__(256) void fused_kernel(
    const float* __restrict__ pred,    // [BT, V]
    const int*   __restrict__ tgt,     // [BT]
    const float* __restrict__ rmask,   // [BT]
    const float* __restrict__ itrue,   // [BL, D]
    const float* __restrict__ ipred,   // [BL, D]
    const float* __restrict__ imask,   // [BL]
    float* __restrict__ part,          // [BT*8]
    float* __restrict__ xt,            // [BT]
    float* __restrict__ mse_out,       // [BL]
    int V, int BT, int D, int BL, int mse_blocks)
{
    const int bid = blockIdx.x;
    const int tid = threadIdx.x;

    if (bid < mse_blocks) {
        // ---------------- MSE: 4 patches per block, one wave each ----------------
        const int lane  = tid & 63;
        const int patch = bid * 4 + (tid >> 6);
        if (patch >= BL) return;
        const float mk = imask[patch];
        if (mk == 0.0f) {
            if (lane == 0) mse_out[patch] = 0.0f;
            return;
        }
        const float4* t4 = (const float4*)(itrue + (size_t)patch * D);
        const float4* p4 = (const float4*)(ipred + (size_t)patch * D);
        const int nd4 = D >> 2;                    // 192
        float acc = 0.0f;
        for (int i = lane; i < nd4; i += 64) {     // 3 iters
            float4 a = t4[i], b = p4[i];
            float dx = b.x - a.x, dy = b.y - a.y, dz = b.z - a.z, dw = b.w - a.w;
            acc += dx * dx + dy * dy + dz * dz + dw * dw;
        }
        #pragma unroll
        for (int off = 32; off > 0; off >>= 1) acc += __shfl_down(acc, off);
        if (lane == 0) mse_out[patch] = acc / (float)D;
        return;
    }

    // ---------------- CE chunk: 1/8 of one vocab row (16 KB) ----------------
    const int cid   = bid - mse_blocks;
    const int row   = cid >> 3;
    const int chunk = cid & 7;
    const float mk  = rmask[row];
    if (mk == 0.0f) {
        if (tid == 0) {
            part[cid] = 0.0f;
            if (chunk == 0) xt[row] = 0.0f;
        }
        return;
    }
    const int VC = V / R_CHUNKS;                   // 4000
    const float4* p4 = (const float4*)(pred + (size_t)row * V + (size_t)chunk * VC);
    const int nv4 = VC >> 2;                       // 1000
    // single pass: each thread 4 contiguous float4 (64B), all 4 loads in flight
    float s0 = 0.f, s1 = 0.f, s2 = 0.f, s3 = 0.f;
    for (int i = tid * 4; i < nv4; i += 1024) {
        const int i1 = min(i + 1, nv4 - 1);
        const int i2 = min(i + 2, nv4 - 1);
        const int i3 = min(i + 3, nv4 - 1);
        float4 a = p4[i], b = p4[i1], c = p4[i2], d = p4[i3];
        s0 += sum4exp(a);
        if (i + 1 < nv4) s1 += sum4exp(b);
        if (i + 2 < nv4) s2 += sum4exp(c);
        if (i + 3 < nv4) s3 += sum4exp(d);
    }
    float s = (s0 + s1) + (s2 + s3);
    #pragma unroll
    for (int off = 32; off > 0; off >>= 1) s += __shfl_down(s, off);

    __shared__ float red[4];
    const int wid = tid >> 6;
    if ((tid & 63) == 0) red[wid] = s;
    __syncthreads();
    if (tid == 0) {
        part[cid] = (red[0] + red[1]) + (red[2] + red[3]);
        if (chunk == 0) xt[row] = pred[(size_t)row * V + tgt[row]];
    }
}

__global__ __launch_bounds__(1024) void finalize_kernel(
    const float* __restrict__ part, const float* __restrict__ xt,
    const float* __restrict__ rmask,
    const float* __restrict__ mse_arr, const float* __restrict__ imask,
    const float* __restrict__ iw, const float* __restrict__ rw,
    float* __restrict__ out, int BT, int BL)
{
    const int tid = threadIdx.x;
    const float4* part4 = (const float4*)part;      // 2 float4 per row
    float a = 0.f, b = 0.f, c = 0.f, d = 0.f;
    for (int r = tid; r < BT; r += 1024) {          // 4 iters
        float mk = rmask[r];
        b += mk;
        if (mk != 0.0f) {
            float4 x = part4[r * 2], y = part4[r * 2 + 1];
            float S = ((x.x + x.y) + (x.z + x.w)) + ((y.x + y.y) + (y.z + y.w));
            a += (__logf(S) - xt[r]) * mk;
        }
    }
    for (int i = tid; i < BL; i += 1024) { c += mse_arr[i]; d += imask[i]; }
    #pragma unroll
    for (int off = 32; off > 0; off >>= 1) {
        a += __shfl_down(a, off); b += __shfl_down(b, off);
        c += __shfl_down(c, off); d += __shfl_down(d, off);
    }
    __shared__ float sa[16], sb[16], sc[16], sd[16];
    const int wid = tid >> 6;
    if ((tid & 63) == 0) { sa[wid] = a; sb[wid] = b; sc[wid] = c; sd[wid] = d; }
    __syncthreads();
    if (tid == 0) {
        float A = 0.f, Bm = 0.f, Cm = 0.f, Dm = 0.f;
        #pragma unroll
        for (int w = 0; w < 16; ++w) { A += sa[w]; Bm += sb[w]; Cm += sc[w]; Dm += sd[w]; }
        out[0] = A / Bm * rw[0] + Cm / Dm * iw[0];
    }
}

extern "C" void kernel_launch(void* const* d_in, const int* in_sizes, int n_in,
                              void* d_out, int out_size, void* d_ws, size_t ws_size,
                              hipStream_t stream) {
    const float* images_true    = (const float*)d_in[0];
    const int*   reports_true   = (const int*)  d_in[1];
    const float* images_pred    = (const float*)d_in[2];
    const float* reports_pred   = (const float*)d_in[3];
    const float* images_mask    = (const float*)d_in[4];
    const float* reports_mask   = (const float*)d_in[5];
    const float* images_weight  = (const float*)d_in[6];
    const float* reports_weight = (const float*)d_in[7];

    float* out = (float*)d_out;
    float* ws  = (float*)d_ws;

    const int BT = in_sizes[1];                 // 4096
    const int V  = in_sizes[3] / BT;            // 32000
    const int BL = in_sizes[4];                 // 6272
    const int D  = in_sizes[0] / BL;            // 768

    float* part    = ws;                                    // [BT*8]
    float* xt      = ws + (size_t)BT * R_CHUNKS;            // [BT]
    float* mse_arr = ws + (size_t)BT * (R_CHUNKS + 1);      // [BL]

    const int mse_blocks = (BL + 3) / 4;                    // 1568
    const int grid = mse_blocks + BT * R_CHUNKS;            // 34336
    fused_kernel<<<grid, 256, 0, stream>>>(
        reports_pred, reports_true, reports_mask,
        images_true, images_pred, images_mask,
        part, xt, mse_arr, V, BT, D, BL, mse_blocks);
    finalize_kernel<<<1, 1024, 0, stream>>>(
        part, xt, reports_mask, mse_arr, images_mask,
        images_weight, reports_weight, out, BT, BL);
}

// Round 6
// 53.535 us; speedup vs baseline: 58.5872x; 1.0207x over previous
//
#include <hip/hip_runtime.h>

#define R_CHUNKS 8

// ws layout (floats):
//   part[BT*8]  at ws[0 .. BT*8)        per-chunk sum(exp(x)) (0 if row masked)
//   xt[BT]      at ws[BT*8 .. BT*9)     target logit per row  (0 if masked)
//   mse[BL]     at ws[BT*9 .. BT*9+BL)  per-patch mse         (0 if masked)
// Every slot written on every call -> no zeroing, graph-replay safe.

__device__ __forceinline__ float sum4exp(float4 v) {
    return __expf(v.x) + __expf(v.y) + __expf(v.z) + __expf(v.w);
}

__global__ __launch_bounds__(256) void fused_kernel(
    const float* __restrict__ pred,    // [BT, V]
    const int*   __restrict__ tgt,     // [BT]
    const float* __restrict__ rmask,   // [BT]
    const float* __restrict__ itrue,   // [BL, D]
    const float* __restrict__ ipred,   // [BL, D]
    const float* __restrict__ imask,   // [BL]
    float* __restrict__ part,          // [BT*8]
    float* __restrict__ xt,            // [BT]
    float* __restrict__ mse_out,       // [BL]
    int V, int BT, int D, int BL, int ce_blocks)
{
    const int bid = blockIdx.x;
    const int tid = threadIdx.x;

    if (bid < ce_blocks) {
        // ---------------- CE chunk: 1/8 of one vocab row (16 KB) ----------------
        const int cid   = bid;
        const int row   = cid >> 3;
        const int chunk = cid & 7;
        const float mk  = rmask[row];
        if (mk == 0.0f) {
            if (tid == 0) {
                part[cid] = 0.0f;
                if (chunk == 0) xt[row] = 0.0f;
            }
            return;
        }
        const int VC  = V / R_CHUNKS;                  // 4000 floats
        const int nv4 = VC >> 2;                       // 1000 float4
        const float4* p4 = (const float4*)(pred + (size_t)row * V + (size_t)chunk * VC);

        // unit-lane-stride: each dwordx4 instr covers 1 KB contiguous per wave.
        // 4 independent loads in flight per thread, single pass over the chunk.
        float s0 = 0.f, s1 = 0.f, s2 = 0.f, s3 = 0.f;
        for (int i = tid; i < nv4; i += 1024) {
            s0 += sum4exp(p4[i]);
            if (i + 256 < nv4) s1 += sum4exp(p4[i + 256]);
            if (i + 512 < nv4) s2 += sum4exp(p4[i + 512]);
            if (i + 768 < nv4) s3 += sum4exp(p4[i + 768]);
        }
        float s = (s0 + s1) + (s2 + s3);
        #pragma unroll
        for (int off = 32; off > 0; off >>= 1) s += __shfl_down(s, off);

        __shared__ float red[4];
        const int wid = tid >> 6;
        if ((tid & 63) == 0) red[wid] = s;
        __syncthreads();
        if (tid == 0) {
            part[cid] = (red[0] + red[1]) + (red[2] + red[3]);
            if (chunk == 0) xt[row] = pred[(size_t)row * V + tgt[row]];
        }
        return;
    }

    // ---------------- MSE: 4 patches per block, one wave each (drain tail) -----
    const int lane  = tid & 63;
    const int patch = (bid - ce_blocks) * 4 + (tid >> 6);
    if (patch >= BL) return;
    const float mk = imask[patch];
    if (mk == 0.0f) {
        if (lane == 0) mse_out[patch] = 0.0f;
        return;
    }
    const float4* t4 = (const float4*)(itrue + (size_t)patch * D);
    const float4* p4 = (const float4*)(ipred + (size_t)patch * D);
    const int nd4 = D >> 2;                    // 192
    float acc = 0.0f;
    for (int i = lane; i < nd4; i += 64) {     // 3 iters
        float4 a = t4[i], b = p4[i];
        float dx = b.x - a.x, dy = b.y - a.y, dz = b.z - a.z, dw = b.w - a.w;
        acc += dx * dx + dy * dy + dz * dz + dw * dw;
    }
    #pragma unroll
    for (int off = 32; off > 0; off >>= 1) acc += __shfl_down(acc, off);
    if (lane == 0) mse_out[patch] = acc / (float)D;
}

__global__ __launch_bounds__(1024) void finalize_kernel(
    const float* __restrict__ part, const float* __restrict__ xt,
    const float* __restrict__ rmask,
    const float* __restrict__ mse_arr, const float* __restrict__ imask,
    const float* __restrict__ iw, const float* __restrict__ rw,
    float* __restrict__ out, int BT, int BL)
{
    const int tid = threadIdx.x;
    const float4* part4 = (const float4*)part;      // 2 float4 per row
    float a = 0.f, b = 0.f, c = 0.f, d = 0.f;
    for (int r = tid; r < BT; r += 1024) {          // 4 iters
        float mk = rmask[r];
        b += mk;
        if (mk != 0.0f) {
            float4 x = part4[r * 2], y = part4[r * 2 + 1];
            float S = ((x.x + x.y) + (x.z + x.w)) + ((y.x + y.y) + (y.z + y.w));
            a += (__logf(S) - xt[r]) * mk;
        }
    }
    for (int i = tid; i < BL; i += 1024) { c += mse_arr[i]; d += imask[i]; }
    #pragma unroll
    for (int off = 32; off > 0; off >>= 1) {
        a += __shfl_down(a, off); b += __shfl_down(b, off);
        c += __shfl_down(c, off); d += __shfl_down(d, off);
    }
    __shared__ float sa[16], sb[16], sc[16], sd[16];
    const int wid = tid >> 6;
    if ((tid & 63) == 0) { sa[wid] = a; sb[wid] = b; sc[wid] = c; sd[wid] = d; }
    __syncthreads();
    if (tid == 0) {
        float A = 0.f, Bm = 0.f, Cm = 0.f, Dm = 0.f;
        #pragma unroll
        for (int w = 0; w < 16; ++w) { A += sa[w]; Bm += sb[w]; Cm += sc[w]; Dm += sd[w]; }
        out[0] = A / Bm * rw[0] + Cm / Dm * iw[0];
    }
}

extern "C" void kernel_launch(void* const* d_in, const int* in_sizes, int n_in,
                              void* d_out, int out_size, void* d_ws, size_t ws_size,
                              hipStream_t stream) {
    const float* images_true    = (const float*)d_in[0];
    const int*   reports_true   = (const int*)  d_in[1];
    const float* images_pred    = (const float*)d_in[2];
    const float* reports_pred   = (const float*)d_in[3];
    const float* images_mask    = (const float*)d_in[4];
    const float* reports_mask   = (const float*)d_in[5];
    const float* images_weight  = (const float*)d_in[6];
    const float* reports_weight = (const float*)d_in[7];

    float* out = (float*)d_out;
    float* ws  = (float*)d_ws;

    const int BT = in_sizes[1];                 // 4096
    const int V  = in_sizes[3] / BT;            // 32000
    const int BL = in_sizes[4];                 // 6272
    const int D  = in_sizes[0] / BL;            // 768

    float* part    = ws;                                    // [BT*8]
    float* xt      = ws + (size_t)BT * R_CHUNKS;            // [BT]
    float* mse_arr = ws + (size_t)BT * (R_CHUNKS + 1);      // [BL]

    const int ce_blocks  = BT * R_CHUNKS;                   // 32768
    const int mse_blocks = (BL + 3) / 4;                    // 1568
    fused_kernel<<<ce_blocks + mse_blocks, 256, 0, stream>>>(
        reports_pred, reports_true, reports_mask,
        images_true, images_pred, images_mask,
        part, xt, mse_arr, V, BT, D, BL, ce_blocks);
    finalize_kernel<<<1, 1024, 0, stream>>>(
        part, xt, reports_mask, mse_arr, images_mask,
        images_weight, reports_weight, out, BT, BL);
}

// Round 8
// 51.574 us; speedup vs baseline: 60.8145x; 1.0380x over previous
//
#include <hip/hip_runtime.h>

#define R_CHUNKS 8

// ws layout (floats):
//   part[BT*8]  at ws[0 .. BT*8)        per-chunk sum(exp(x)) (0 if row masked)
//   xt[BT]      at ws[BT*8 .. BT*9)     target logit per row  (0 if masked)
//   mse[BL]     at ws[BT*9 .. BT*9+BL)  per-patch mse         (0 if masked)
// Every slot written on every call -> no zeroing, graph-replay safe.

typedef float floatx4 __attribute__((ext_vector_type(4)));

__device__ __forceinline__ floatx4 nt_load4(const float* p) {
    // single-use stream: non-temporal hint keeps it from thrashing L1/L2
    return __builtin_nontemporal_load((const floatx4*)p);
}

__device__ __forceinline__ float sum4exp(floatx4 v) {
    return __expf(v.x) + __expf(v.y) + __expf(v.z) + __expf(v.w);
}

__global__ __launch_bounds__(256) void fused_kernel(
    const float* __restrict__ pred,    // [BT, V]
    const int*   __restrict__ tgt,     // [BT]
    const float* __restrict__ rmask,   // [BT]
    const float* __restrict__ itrue,   // [BL, D]
    const float* __restrict__ ipred,   // [BL, D]
    const float* __restrict__ imask,   // [BL]
    float* __restrict__ part,          // [BT*8]
    float* __restrict__ xt,            // [BT]
    float* __restrict__ mse_out,       // [BL]
    int V, int BT, int D, int BL, int ce_blocks)
{
    const int bid = blockIdx.x;
    const int tid = threadIdx.x;

    if (bid < ce_blocks) {
        // ---------------- CE chunk: 1/8 of one vocab row (16 KB) ----------------
        const int cid   = bid;
        const int row   = cid >> 3;
        const int chunk = cid & 7;
        const float mk  = rmask[row];
        if (mk == 0.0f) {
            if (tid == 0) {
                part[cid] = 0.0f;
                if (chunk == 0) xt[row] = 0.0f;
            }
            return;
        }
        const int VC  = V / R_CHUNKS;                  // 4000 floats
        const int nv4 = VC >> 2;                       // 1000 float4
        const float* p = pred + (size_t)row * V + (size_t)chunk * VC;

        // unit-lane-stride: each dwordx4 instr covers 1 KB contiguous per wave.
        // 4 independent nt loads in flight per thread, single pass.
        float s0 = 0.f, s1 = 0.f, s2 = 0.f, s3 = 0.f;
        for (int i = tid; i < nv4; i += 1024) {
            s0 += sum4exp(nt_load4(p + 4 * i));
            if (i + 256 < nv4) s1 += sum4exp(nt_load4(p + 4 * (i + 256)));
            if (i + 512 < nv4) s2 += sum4exp(nt_load4(p + 4 * (i + 512)));
            if (i + 768 < nv4) s3 += sum4exp(nt_load4(p + 4 * (i + 768)));
        }
        float s = (s0 + s1) + (s2 + s3);
        #pragma unroll
        for (int off = 32; off > 0; off >>= 1) s += __shfl_down(s, off);

        __shared__ float red[4];
        const int wid = tid >> 6;
        if ((tid & 63) == 0) red[wid] = s;
        __syncthreads();
        if (tid == 0) {
            part[cid] = (red[0] + red[1]) + (red[2] + red[3]);
            if (chunk == 0) xt[row] = pred[(size_t)row * V + tgt[row]];
        }
        return;
    }

    // ---------------- MSE: 4 patches per block, one wave each (drain tail) -----
    const int lane  = tid & 63;
    const int patch = (bid - ce_blocks) * 4 + (tid >> 6);
    if (patch >= BL) return;
    const float mk = imask[patch];
    if (mk == 0.0f) {
        if (lane == 0) mse_out[patch] = 0.0f;
        return;
    }
    const float* tp = itrue + (size_t)patch * D;
    const float* pp = ipred + (size_t)patch * D;
    const int nd4 = D >> 2;                    // 192
    float acc = 0.0f;
    for (int i = lane; i < nd4; i += 64) {     // 3 iters
        floatx4 a = nt_load4(tp + 4 * i), b = nt_load4(pp + 4 * i);
        float dx = b.x - a.x, dy = b.y - a.y, dz = b.z - a.z, dw = b.w - a.w;
        acc += dx * dx + dy * dy + dz * dz + dw * dw;
    }
    #pragma unroll
    for (int off = 32; off > 0; off >>= 1) acc += __shfl_down(acc, off);
    if (lane == 0) mse_out[patch] = acc / (float)D;
}

__global__ __launch_bounds__(1024) void finalize_kernel(
    const float* __restrict__ part, const float* __restrict__ xt,
    const float* __restrict__ rmask,
    const float* __restrict__ mse_arr, const float* __restrict__ imask,
    const float* __restrict__ iw, const float* __restrict__ rw,
    float* __restrict__ out, int BT, int BL)
{
    const int tid = threadIdx.x;
    const float4* part4 = (const float4*)part;      // 2 float4 per row
    float a = 0.f, b = 0.f, c = 0.f, d = 0.f;
    for (int r = tid; r < BT; r += 1024) {          // 4 iters
        float mk = rmask[r];
        b += mk;
        if (mk != 0.0f) {
            float4 x = part4[r * 2], y = part4[r * 2 + 1];
            float S = ((x.x + x.y) + (x.z + x.w)) + ((y.x + y.y) + (y.z + y.w));
            a += (__logf(S) - xt[r]) * mk;
        }
    }
    for (int i = tid; i < BL; i += 1024) { c += mse_arr[i]; d += imask[i]; }
    #pragma unroll
    for (int off = 32; off > 0; off >>= 1) {
        a += __shfl_down(a, off); b += __shfl_down(b, off);
        c += __shfl_down(c, off); d += __shfl_down(d, off);
    }
    __shared__ float sa[16], sb[16], sc[16], sd[16];
    const int wid = tid >> 6;
    if ((tid & 63) == 0) { sa[wid] = a; sb[wid] = b; sc[wid] = c; sd[wid] = d; }
    __syncthreads();
    if (tid == 0) {
        float A = 0.f, Bm = 0.f, Cm = 0.f, Dm = 0.f;
        #pragma unroll
        for (int w = 0; w < 16; ++w) { A += sa[w]; Bm += sb[w]; Cm += sc[w]; Dm += sd[w]; }
        out[0] = A / Bm * rw[0] + Cm / Dm * iw[0];
    }
}

extern "C" void kernel_launch(void* const* d_in, const int* in_sizes, int n_in,
                              void* d_out, int out_size, void* d_ws, size_t ws_size,
                              hipStream_t stream) {
    const float* images_true    = (const float*)d_in[0];
    const int*   reports_true   = (const int*)  d_in[1];
    const float* images_pred    = (const float*)d_in[2];
    const float* reports_pred   = (const float*)d_in[3];
    const float* images_mask    = (const float*)d_in[4];
    const float* reports_mask   = (const float*)d_in[5];
    const float* images_weight  = (const float*)d_in[6];
    const float* reports_weight = (const float*)d_in[7];

    float* out = (float*)d_out;
    float* ws  = (float*)d_ws;

    const int BT = in_sizes[1];                 // 4096
    const int V  = in_sizes[3] / BT;            // 32000
    const int BL = in_sizes[4];                 // 6272
    const int D  = in_sizes[0] / BL;            // 768

    float* part    = ws;                                    // [BT*8]
    float* xt      = ws + (size_t)BT * R_CHUNKS;            // [BT]
    float* mse_arr = ws + (size_t)BT * (R_CHUNKS + 1);      // [BL]

    const int ce_blocks  = BT * R_CHUNKS;                   // 32768
    const int mse_blocks = (BL + 3) / 4;                    // 1568
    fused_kernel<<<ce_blocks + mse_blocks, 256, 0, stream>>>(
        reports_pred, reports_true, reports_mask,
        images_true, images_pred, images_mask,
        part, xt, mse_arr, V, BT, D, BL, ce_blocks);
    finalize_kernel<<<1, 1024, 0, stream>>>(
        part, xt, reports_mask, mse_arr, images_mask,
        images_weight, reports_weight, out, BT, BL);
}